// Round 7
// baseline (332.909 us; speedup 1.0000x reference)
//
#include <hip/hip_runtime.h>
#include <math.h>

typedef unsigned short u16;
typedef float f32x4 __attribute__((ext_vector_type(4)));
typedef short s16x4 __attribute__((ext_vector_type(4)));
typedef short s16x8 __attribute__((ext_vector_type(8)));

#define AS3 __attribute__((address_space(3)))
#define AS1 __attribute__((address_space(1)))

__device__ __forceinline__ u16 f2bf(float f) {
  unsigned x = __builtin_bit_cast(unsigned, f);
  x += 0x7fffu + ((x >> 16) & 1u);
  return (u16)(x >> 16);
}
__device__ __forceinline__ float bf2f(u16 u) {
  unsigned x = ((unsigned)u) << 16;
  return __builtin_bit_cast(float, x);
}
__device__ __forceinline__ void gload16(const void* g, void* l) {
  __builtin_amdgcn_global_load_lds((const AS1 void*)g, (AS3 void*)l, 16, 0, 0);
}

// ---------------- adjacency preprocessing ----------------
__global__ void k_dinv(const float* __restrict__ adj, float* __restrict__ dinv) {
  int j = blockIdx.x;
  float s = 0.0f;
  for (int i = threadIdx.x; i < 512; i += 64) s += adj[(size_t)j * 512 + i];
  #pragma unroll
  for (int off = 32; off > 0; off >>= 1) s += __shfl_down(s, off);
  if (threadIdx.x == 0) dinv[j] = 1.0f / (1.0f + s);
}

// Ab[n][m] = (adj[m][n] + (n==m)) * dinv[m]   (random-walk transpose), bf16
__global__ void k_buildA(const float* __restrict__ adj, const float* __restrict__ dinv,
                         u16* __restrict__ Ab) {
  int i = blockIdx.x;
  for (int j = threadIdx.x; j < 512; j += 256) {
    float v = adj[(size_t)j * 512 + i] + ((i == j) ? 1.0f : 0.0f);
    Ab[(size_t)i * 512 + j] = f2bf(v * dinv[j]);
  }
}

// state fp32 -> node-major bf16 (XG0n) AND f-major bf16 (XG0t), one read
__global__ __launch_bounds__(256) void k_prepST(const float* __restrict__ s,
                                                u16* __restrict__ Xn,
                                                u16* __restrict__ Xt) {
  __shared__ float Tl[64][65];
  const int b = blockIdx.y, n0 = blockIdx.x * 64;
  const int tid = threadIdx.x;
  const int r = tid >> 4, c4 = (tid & 15) * 4;
  #pragma unroll
  for (int i = 0; i < 4; ++i) {
    f32x4 v = *(const f32x4*)&s[((size_t)b * 512 + n0 + i * 16 + r) * 64 + c4];
    s16x4 o;
    #pragma unroll
    for (int j = 0; j < 4; ++j) { Tl[c4 + j][i * 16 + r] = v[j]; o[j] = (short)f2bf(v[j]); }
    *(s16x4*)&Xn[((size_t)b * 512 + n0 + i * 16 + r) * 64 + c4] = o;
  }
  __syncthreads();
  #pragma unroll
  for (int i = 0; i < 4; ++i) {
    int d = i * 16 + r;
    s16x4 o;
    #pragma unroll
    for (int j = 0; j < 4; ++j) o[j] = (short)f2bf(Tl[d][c4 + j]);
    *(s16x4*)&Xt[((size_t)b * 64 + d) * 512 + n0 + c4] = o;
  }
}

// inp[b][m*2+c] -> Xi0t[(b*2+c)*512 + m]  (bf16, channel-major rows; Xi0t = XAll0t tail)
__global__ void k_prepI(const float* __restrict__ inp, u16* __restrict__ Xi0t) {
  const int b = blockIdx.x, t = threadIdx.x;
  const int m2 = t * 2;
  f32x4 v = *(const f32x4*)&inp[(size_t)b * 1024 + m2 * 2];
  unsigned p0 = (unsigned)f2bf(v.x) | ((unsigned)f2bf(v.z) << 16);
  unsigned p1 = (unsigned)f2bf(v.y) | ((unsigned)f2bf(v.w) << 16);
  *(unsigned*)&Xi0t[((size_t)b * 2 + 0) * 512 + m2] = p0;
  *(unsigned*)&Xi0t[((size_t)b * 2 + 1) * 512 + m2] = p1;
}

// WTp[col][kt][g][j] permuted per-thread A-fragments, with Chebyshev WEIGHT FOLDING:
// k1==0 -> W0 - W2 ; k1==1 -> W1 ; k1==2 -> 2*W2  (so hop2 output is plain A@X1)
template<int NC>
__global__ void k_wtp(const float* __restrict__ W, u16* __restrict__ WTp) {
  int col = blockIdx.x, tid = threadIdx.x;
  if (tid >= 224) return;
  int kt = tid >> 5, g = (tid >> 3) & 3, j = tid & 7;
  int kappa = 32 * kt + 4 * g + ((j < 4) ? j : j + 12);
  float v = 0.0f;
  if (kappa < 192) {
    int f = kappa & 63, k1 = kappa >> 6;
    const float* base = &W[(size_t)((f + 2) * 3) * NC + col];
    v = (k1 == 0) ? base[0] - base[2 * NC]
      : (k1 == 1) ? base[1 * NC]
                  : 2.0f * base[2 * NC];
  } else if (kappa < 198) {
    int t = kappa - 192, k1 = t >> 1, c = t & 1;
    const float* base = &W[(size_t)(c * 3) * NC + col];
    v = (k1 == 0) ? base[0] - base[2 * NC]
      : (k1 == 1) ? base[1 * NC]
                  : 2.0f * base[2 * NC];
  }
  WTp[(size_t)col * 224 + tid] = f2bf(v);
}

// ---------------- diffusion GEMM (hop1 / input-hop2): Yt[R][n] = sum_m Xt[R][m]*Ab[n][m]
template<int WTB, int WNB>
__global__ __launch_bounds__(256, 3) void k_diffB(const u16* __restrict__ Xt,
                                                  const u16* __restrict__ Ab,
                                                  u16* __restrict__ Yt,
                                                  u16* __restrict__ Yn) {
  __shared__ __align__(16) u16 SB[16384];
  const int tid = threadIdx.x;
  const int w = tid >> 6, l = tid & 63, g = l >> 4, l16 = l & 15;
  const int Rg = w >> 1, ng = w & 1;
  const int nt0 = blockIdx.x * 128;
  const size_t R0 = (size_t)blockIdx.y * 128;
  const bool isInput = (R0 >= 16384);
  f32x4 acc[4][4] = {};

#define STAGE(BUF, M0)                                                            \
  {                                                                               \
    _Pragma("unroll")                                                             \
    for (int i_ = 0; i_ < 2; ++i_) {                                              \
      int s_ = i_ * 256 + tid, r_ = s_ >> 2, p_ = s_ & 3;                         \
      gload16(&Xt[(R0 + r_) * 512 + (M0) + 8 * (p_ ^ (r_ & 3))],                  \
              &SB[(BUF) * 4096 + s_ * 8]);                                        \
      gload16(&Ab[(size_t)(nt0 + r_) * 512 + (M0) + 8 * (p_ ^ (r_ & 3))],         \
              &SB[8192 + (BUF) * 4096 + s_ * 8]);                                 \
    }                                                                             \
  }

  STAGE(0, 0);
  #pragma unroll
  for (int it = 0; it < 16; ++it) {
    const int cur = it & 1;
    if (it < 15) {
      if (cur == 0) STAGE(1, (it + 1) * 32)
      else          STAGE(0, (it + 1) * 32)
      asm volatile("s_waitcnt vmcnt(4)" ::: "memory");
    } else {
      asm volatile("s_waitcnt vmcnt(0)" ::: "memory");
    }
    __builtin_amdgcn_s_barrier();
    __builtin_amdgcn_sched_barrier(0);

    const u16* XL = &SB[cur * 4096];
    const u16* AL = &SB[8192 + cur * 4096];
    s16x8 af[4], bf[4];
    #pragma unroll
    for (int mt = 0; mt < 4; ++mt) {
      int r = Rg * 64 + mt * 16 + l16;
      const char* rowp = (const char*)XL + r * 64 + 8 * (g & 1);
      int c0 = (g >> 1), c1 = c0 + 2;
      s16x4 lo = *(const s16x4*)(rowp + 16 * (c0 ^ (r & 3)));
      s16x4 hi = *(const s16x4*)(rowp + 16 * (c1 ^ (r & 3)));
      af[mt] = __builtin_shufflevector(lo, hi, 0, 1, 2, 3, 4, 5, 6, 7);
    }
    #pragma unroll
    for (int nt = 0; nt < 4; ++nt) {
      int r = ng * 64 + nt * 16 + l16;
      const char* rowp = (const char*)AL + r * 64 + 8 * (g & 1);
      int c0 = (g >> 1), c1 = c0 + 2;
      s16x4 lo = *(const s16x4*)(rowp + 16 * (c0 ^ (r & 3)));
      s16x4 hi = *(const s16x4*)(rowp + 16 * (c1 ^ (r & 3)));
      bf[nt] = __builtin_shufflevector(lo, hi, 0, 1, 2, 3, 4, 5, 6, 7);
    }
    #pragma unroll
    for (int mt = 0; mt < 4; ++mt)
      #pragma unroll
      for (int nt = 0; nt < 4; ++nt)
        acc[mt][nt] = __builtin_amdgcn_mfma_f32_16x16x32_bf16(af[mt], bf[nt],
                                                              acc[mt][nt], 0, 0, 0);
    __builtin_amdgcn_s_barrier();
    __builtin_amdgcn_sched_barrier(0);
  }
#undef STAGE

  if (WNB && !isInput) {
    #pragma unroll
    for (int mt = 0; mt < 4; ++mt)
      #pragma unroll
      for (int nt = 0; nt < 4; ++nt) {
        size_t R = R0 + Rg * 64 + mt * 16 + 4 * g;
        int n = nt0 + ng * 64 + nt * 16 + l16;
        s16x4 o;
        #pragma unroll
        for (int rr = 0; rr < 4; ++rr) o[rr] = (short)f2bf(acc[mt][nt][rr]);
        *(s16x4*)&Yn[((R >> 6) * 512 + n) * 64 + (R & 63)] = o;
      }
  }

  if (WTB || isInput) {
    #pragma unroll
    for (int mt = 0; mt < 4; ++mt)
      #pragma unroll
      for (int nt = 0; nt < 4; ++nt) {
        int nl = ng * 64 + nt * 16 + l16;
        #pragma unroll
        for (int rr = 0; rr < 4; ++rr) {
          int Rl = Rg * 64 + mt * 16 + 4 * g + rr;
          SB[Rl * 128 + nl] = f2bf(acc[mt][nt][rr]);
        }
      }
    __syncthreads();
    #pragma unroll
    for (int i = 0; i < 8; ++i) {
      int s = i * 256 + tid, r = s >> 4, c = s & 15;
      *(s16x8*)&Yt[(R0 + r) * 512 + nt0 + c * 8] = *(const s16x8*)&SB[r * 128 + c * 8];
    }
  }
}

// ---------------- fused hop2 + applyW ----------------
// Diffusion: Z = A@X1 over 128R(=2 batches x 64f) x 128n, acc in regs.
// Apply (per batch): out[col][n] = act( sum_kappa WTp[col][kappa] * S[kappa][n] )
//   S tiles: S0 (state / r*state, staged node-major), S1 (X1n staged), S2 (Z via LDS
//   transpose into the proven swizzled layout), tail (inp/Yi1/Yi2).
// LDS 64KB: [0:16K)=dbuf lo (Xl) then S1; [16K:32K)=dbuf hi (Ab) split at 8192: St@[8192x u16]
//   u16 map: S1OFF=0, STOFF=8192, S0OFF=16384, S2OFF=24576 (dbuf = [0..16383] u16)
template<int ISGATE>
__global__ __launch_bounds__(256, 2) void k_fuse(
    const u16* __restrict__ Xt, const u16* __restrict__ Ab,
    const u16* __restrict__ S0src, const u16* __restrict__ S1src,
    const float* __restrict__ inp, const u16* __restrict__ Yi1, const u16* __restrict__ Yi2,
    const u16* __restrict__ WTp, const float* __restrict__ bias,
    const u16* __restrict__ SnState, const float* __restrict__ statef,
    const u16* __restrict__ Ubin,
    u16* __restrict__ XC0n, u16* __restrict__ XC0t, u16* __restrict__ Ubout,
    float* __restrict__ outp) {
  __shared__ __align__(16) u16 SB[32768];
  const int tid = threadIdx.x;
  const int w = tid >> 6, l = tid & 63, g = l >> 4, l16 = l & 15;
  const int Rg = w >> 1, ng = w & 1;
  const int nt0 = blockIdx.x * 128;
  const size_t R0 = (size_t)blockIdx.y * 128;
  f32x4 facc[4][4] = {};

#define FSTAGE(BUF, M0)                                                           \
  {                                                                               \
    _Pragma("unroll")                                                             \
    for (int i_ = 0; i_ < 2; ++i_) {                                              \
      int s_ = i_ * 256 + tid, r_ = s_ >> 2, p_ = s_ & 3;                         \
      gload16(&Xt[(R0 + r_) * 512 + (M0) + 8 * (p_ ^ (r_ & 3))],                  \
              &SB[(BUF) * 4096 + s_ * 8]);                                        \
      gload16(&Ab[(size_t)(nt0 + r_) * 512 + (M0) + 8 * (p_ ^ (r_ & 3))],         \
              &SB[8192 + (BUF) * 4096 + s_ * 8]);                                 \
    }                                                                             \
  }

  FSTAGE(0, 0);
  #pragma unroll
  for (int it = 0; it < 16; ++it) {
    const int cur = it & 1;
    if (it < 15) {
      if (cur == 0) FSTAGE(1, (it + 1) * 32)
      else          FSTAGE(0, (it + 1) * 32)
      asm volatile("s_waitcnt vmcnt(4)" ::: "memory");
    } else {
      asm volatile("s_waitcnt vmcnt(0)" ::: "memory");
    }
    __builtin_amdgcn_s_barrier();
    __builtin_amdgcn_sched_barrier(0);

    const u16* XL = &SB[cur * 4096];
    const u16* AL = &SB[8192 + cur * 4096];
    s16x8 af[4], bf[4];
    #pragma unroll
    for (int mt = 0; mt < 4; ++mt) {
      int r = Rg * 64 + mt * 16 + l16;
      const char* rowp = (const char*)XL + r * 64 + 8 * (g & 1);
      int c0 = (g >> 1), c1 = c0 + 2;
      s16x4 lo = *(const s16x4*)(rowp + 16 * (c0 ^ (r & 3)));
      s16x4 hi = *(const s16x4*)(rowp + 16 * (c1 ^ (r & 3)));
      af[mt] = __builtin_shufflevector(lo, hi, 0, 1, 2, 3, 4, 5, 6, 7);
    }
    #pragma unroll
    for (int nt = 0; nt < 4; ++nt) {
      int r = ng * 64 + nt * 16 + l16;
      const char* rowp = (const char*)AL + r * 64 + 8 * (g & 1);
      int c0 = (g >> 1), c1 = c0 + 2;
      s16x4 lo = *(const s16x4*)(rowp + 16 * (c0 ^ (r & 3)));
      s16x4 hi = *(const s16x4*)(rowp + 16 * (c1 ^ (r & 3)));
      bf[nt] = __builtin_shufflevector(lo, hi, 0, 1, 2, 3, 4, 5, 6, 7);
    }
    #pragma unroll
    for (int mt = 0; mt < 4; ++mt)
      #pragma unroll
      for (int nt = 0; nt < 4; ++nt)
        facc[mt][nt] = __builtin_amdgcn_mfma_f32_16x16x32_bf16(af[mt], bf[nt],
                                                               facc[mt][nt], 0, 0, 0);
    __builtin_amdgcn_s_barrier();
    __builtin_amdgcn_sched_barrier(0);
  }
#undef FSTAGE

  // W fragments -> registers
  constexpr int NCF = ISGATE ? 2 : 1;
  s16x8 aw[7][NCF];
  #pragma unroll
  for (int cf = 0; cf < NCF; ++cf) {
    const u16* wp = WTp + (size_t)((ISGATE ? w * 32 : w * 16) + cf * 16 + l16) * 224 + g * 8;
    #pragma unroll
    for (int kt = 0; kt < 7; ++kt) aw[kt][cf] = *(const s16x8*)&wp[kt * 32];
  }

  #pragma unroll
  for (int bb = 0; bb < 2; ++bb) {
    const int b = (int)(R0 >> 6) + bb;
    if (bb == 0) {
      #pragma unroll
      for (int it = 0; it < 4; ++it) {
        int s = it * 256 + tid, r = s >> 3, p = s & 7;
        size_t gidx = ((size_t)b * 512 + nt0 + r) * 64 + 8 * (p ^ (r & 7));
        gload16(&S0src[gidx], &SB[16384 + (it * 256 + w * 64) * 8]);
        gload16(&S1src[gidx], &SB[0 + (it * 256 + w * 64) * 8]);
      }
      for (int i = tid; i < 4608; i += 256)
        if ((i % 36) >= 6) SB[8192 + i] = 0;
    }
    // tail tile [128 n][36]
    for (int t = tid; t < 768; t += 256) {
      int p = t >> 7, nn = t & 127;
      int k1 = p >> 1, c = p & 1;
      int n = nt0 + nn;
      u16 v;
      if (k1 == 0) v = f2bf(inp[(size_t)b * 1024 + n * 2 + c]);
      else v = ((k1 == 1) ? Yi1 : Yi2)[((size_t)b * 2 + c) * 512 + n];
      SB[8192 + nn * 36 + p] = v;
    }
    // S2 = Z transpose (waves owning this batch), swizzled node-major
    if (Rg == bb) {
      #pragma unroll
      for (int mt = 0; mt < 4; ++mt)
        #pragma unroll
        for (int nt = 0; nt < 4; ++nt) {
          int nl = ng * 64 + nt * 16 + l16;
          #pragma unroll
          for (int rr = 0; rr < 4; ++rr) {
            int f = mt * 16 + 4 * g + rr;
            int cc = f >> 3;
            SB[24576 + nl * 64 + ((cc ^ (nl & 7)) << 3) + (f & 7)] =
                f2bf(facc[mt][nt][rr]);
          }
        }
    }
    asm volatile("s_waitcnt vmcnt(0)" ::: "memory");
    __syncthreads();

    // apply GEMM
    f32x4 aacc[NCF][8];
    #pragma unroll
    for (int cf = 0; cf < NCF; ++cf)
      #pragma unroll
      for (int ns = 0; ns < 8; ++ns) aacc[cf][ns] = f32x4{0.f, 0.f, 0.f, 0.f};
    #pragma unroll
    for (int kt = 0; kt < 7; ++kt) {
      #pragma unroll
      for (int ns = 0; ns < 8; ++ns) {
        int rn = ns * 16 + l16;
        s16x4 lo, hi;
        if (kt < 6) {
          int off = (kt < 2) ? 16384 : (kt < 4) ? 0 : 24576;
          int ft = kt & 1;
          const char* rowp = (const char*)&SB[off] + rn * 128 + 8 * (g & 1);
          int c0 = ft * 4 + (g >> 1), c1 = c0 + 2;
          lo = *(const s16x4*)(rowp + 16 * (c0 ^ (rn & 7)));
          hi = *(const s16x4*)(rowp + 16 * (c1 ^ (rn & 7)));
        } else {
          const char* rowp = (const char*)&SB[8192] + rn * 72 + 8 * g;
          lo = *(const s16x4*)rowp;
          hi = *(const s16x4*)(rowp + 32);
        }
        s16x8 bs = __builtin_shufflevector(lo, hi, 0, 1, 2, 3, 4, 5, 6, 7);
        #pragma unroll
        for (int cf = 0; cf < NCF; ++cf)
          aacc[cf][ns] = __builtin_amdgcn_mfma_f32_16x16x32_bf16(aw[kt][cf], bs,
                                                                 aacc[cf][ns], 0, 0, 0);
      }
    }
    __syncthreads();

    if (bb == 0) {  // prefetch next batch's S0/S1 (regions now free)
      #pragma unroll
      for (int it = 0; it < 4; ++it) {
        int s = it * 256 + tid, r = s >> 3, p = s & 7;
        size_t gidx = ((size_t)(b + 1) * 512 + nt0 + r) * 64 + 8 * (p ^ (r & 7));
        gload16(&S0src[gidx], &SB[16384 + (it * 256 + w * 64) * 8]);
        gload16(&S1src[gidx], &SB[0 + (it * 256 + w * 64) * 8]);
      }
    }

    if (ISGATE) {
      if (w < 2) {  // r-half: cols 0..63
        #pragma unroll
        for (int cf = 0; cf < NCF; ++cf) {
          int col0 = w * 32 + cf * 16 + 4 * g;
          f32x4 b4 = *(const f32x4*)&bias[col0];
          #pragma unroll
          for (int ns = 0; ns < 8; ++ns) {
            int nl = ns * 16 + l16;
            size_t base = ((size_t)b * 512 + nt0 + nl) * 64 + col0;
            s16x4 st4 = *(const s16x4*)&SnState[base];
            s16x4 o;
            #pragma unroll
            for (int rr = 0; rr < 4; ++rr) {
              float x = aacc[cf][ns][rr] + b4[rr];
              float sg = 1.0f / (1.0f + expf(-x));
              o[rr] = (short)f2bf(sg * bf2f((u16)st4[rr]));
            }
            *(s16x4*)&XC0n[base] = o;
            #pragma unroll
            for (int rr = 0; rr < 4; ++rr)
              SB[24576 + (col0 + rr) * 128 + nl] = (u16)o[rr];  // bounce [64f][128n]
          }
        }
      } else {  // u-half: cols 64..127
        #pragma unroll
        for (int cf = 0; cf < NCF; ++cf) {
          int col0 = w * 32 + cf * 16 + 4 * g;
          f32x4 b4 = *(const f32x4*)&bias[col0];
          #pragma unroll
          for (int ns = 0; ns < 8; ++ns) {
            int n = nt0 + ns * 16 + l16;
            size_t base = ((size_t)b * 512 + n) * 64 + (col0 - 64);
            s16x4 uo;
            #pragma unroll
            for (int rr = 0; rr < 4; ++rr) {
              float x = aacc[cf][ns][rr] + b4[rr];
              uo[rr] = (short)f2bf(1.0f / (1.0f + expf(-x)));
            }
            *(s16x4*)&Ubout[base] = uo;
          }
        }
      }
      __syncthreads();
      #pragma unroll
      for (int i2 = 0; i2 < 4; ++i2) {
        int s = i2 * 256 + tid, f = s >> 4, cc = s & 15;
        *(s16x8*)&XC0t[((size_t)b * 64 + f) * 512 + nt0 + cc * 8] =
            *(const s16x8*)&SB[24576 + f * 128 + cc * 8];
      }
      __syncthreads();
    } else {
      int col0 = w * 16 + 4 * g;
      f32x4 b4 = *(const f32x4*)&bias[col0];
      #pragma unroll
      for (int ns = 0; ns < 8; ++ns) {
        int n = nt0 + ns * 16 + l16;
        size_t base = ((size_t)b * 512 + n) * 64 + col0;
        s16x4 ub4 = *(const s16x4*)&Ubin[base];
        f32x4 st4 = *(const f32x4*)&statef[base];
        f32x4 o;
        #pragma unroll
        for (int rr = 0; rr < 4; ++rr) {
          float c = tanhf(aacc[0][ns][rr] + b4[rr]);
          float u = bf2f((u16)ub4[rr]);
          o[rr] = fmaf(u, st4[rr] - c, c);
        }
        *(f32x4*)&outp[base] = o;
      }
    }
  }
}

extern "C" void kernel_launch(void* const* d_in, const int* in_sizes, int n_in,
                              void* d_out, int out_size, void* d_ws, size_t ws_size,
                              hipStream_t stream) {
  const float* inp   = (const float*)d_in[0];
  const float* state = (const float*)d_in[1];
  const float* adj   = (const float*)d_in[2];
  const float* Wg    = (const float*)d_in[3];
  const float* bg    = (const float*)d_in[4];
  const float* Wc    = (const float*)d_in[5];
  const float* bc    = (const float*)d_in[6];
  float* out = (float*)d_out;

  char* p = (char*)d_ws;
  u16* Abf    = (u16*)p; p += 524288;      // Ab[n][m]
  u16* XAll0t = (u16*)p; p += 17301504;    // [16896][512]: XG0t (later XC0t) + Xi0t tail
  u16* X1t    = (u16*)p; p += 17301504;    // [16896][512]: X1t batch + Yi1t tail
  u16* Yi2t   = (u16*)p; p += 524288;      // [512][512]  (now plain A@Yi1, weights folded)
  u16* WTpg   = (u16*)p; p += 57344;       // [128][224] permuted + folded
  u16* WTpc   = (u16*)p; p += 28672;       // [64][224]
  float* dinv = (float*)p; p += 2048;
  u16* XG0n   = (u16*)p; p += 16777216;    // [b][n][64] state bf16 node-major
  u16* XC0n   = (u16*)p; p += 16777216;    // r*state node-major
  u16* X1n    = (u16*)p; p += 16777216;
  u16* Ub     = (u16*)p; p += 16777216;    // u gate bf16  (total ~98.1 MB)
  u16* Xi0t   = XAll0t + (size_t)16384 * 512;
  u16* XC0t   = XAll0t;                    // alias: XG0t dead after gate hop1
  u16* Yi1t   = X1t + (size_t)16384 * 512;

  k_dinv   <<<512, 64,  0, stream>>>(adj, dinv);
  k_buildA <<<512, 256, 0, stream>>>(adj, dinv, Abf);
  k_prepST <<<dim3(8, 256), 256, 0, stream>>>(state, XG0n, XAll0t);
  k_prepI  <<<256, 256, 0, stream>>>(inp, Xi0t);
  k_wtp<128><<<128, 256, 0, stream>>>(Wg, WTpg);
  k_wtp<64> <<<64, 256, 0, stream>>>(Wc, WTpc);

  // gate hop1 (batch + input rows) -> X1t (+Yi1t tail), X1n
  k_diffB<1, 1><<<dim3(4, 132), 256, 0, stream>>>(XAll0t, Abf, X1t, X1n);
  // input hop2: Yi2 = A @ Yi1 (plain; Chebyshev folded into weights)
  k_diffB<1, 0><<<dim3(4, 4), 256, 0, stream>>>(Yi1t, Abf, Yi2t, nullptr);
  // fused gate hop2 + applyG -> XC0n, XC0t, Ub
  k_fuse<1><<<dim3(4, 128), 256, 0, stream>>>(X1t, Abf, XG0n, X1n, inp, Yi1t, Yi2t,
                                              WTpg, bg, XG0n, nullptr, nullptr,
                                              XC0n, XC0t, Ub, nullptr);
  // cand hop1 (batch rows) -> X1t, X1n   (Yi1t tail untouched)
  k_diffB<1, 1><<<dim3(4, 128), 256, 0, stream>>>(XC0t, Abf, X1t, X1n);
  // fused cand hop2 + applyC -> out
  k_fuse<0><<<dim3(4, 128), 256, 0, stream>>>(X1t, Abf, XC0n, X1n, inp, Yi1t, Yi2t,
                                              WTpc, bc, nullptr, state, Ub,
                                              nullptr, nullptr, nullptr, out);
}

// Round 8
// 242.255 us; speedup vs baseline: 1.3742x; 1.3742x over previous
//
#include <hip/hip_runtime.h>
#include <math.h>

typedef unsigned short u16;
typedef float f32x4 __attribute__((ext_vector_type(4)));
typedef short s16x4 __attribute__((ext_vector_type(4)));
typedef short s16x8 __attribute__((ext_vector_type(8)));

#define AS3 __attribute__((address_space(3)))
#define AS1 __attribute__((address_space(1)))

__device__ __forceinline__ u16 f2bf(float f) {
  unsigned x = __builtin_bit_cast(unsigned, f);
  x += 0x7fffu + ((x >> 16) & 1u);
  return (u16)(x >> 16);
}
__device__ __forceinline__ float bf2f(u16 u) {
  unsigned x = ((unsigned)u) << 16;
  return __builtin_bit_cast(float, x);
}
__device__ __forceinline__ void gload16(const void* g, void* l) {
  __builtin_amdgcn_global_load_lds((const AS1 void*)g, (AS3 void*)l, 16, 0, 0);
}

// SnAll row: 224 u16 per (b,n). kappa 0-63 = S0 (state/rs), 64-127 = X1, 128-191 = X2,
// 192-197 = tail (inp,Yi1,Yi2), 198-223 = zero-weighted junk. Stored as 28 16B chunks,
// chunk c at position p = c<24 ? c^(n&7) : 24+((c-24)^(n&3))  (proven involution).

// ---------------- adjacency preprocessing ----------------
__global__ void k_dinv(const float* __restrict__ adj, float* __restrict__ dinv) {
  int j = blockIdx.x;
  float s = 0.0f;
  for (int i = threadIdx.x; i < 512; i += 64) s += adj[(size_t)j * 512 + i];
  #pragma unroll
  for (int off = 32; off > 0; off >>= 1) s += __shfl_down(s, off);
  if (threadIdx.x == 0) dinv[j] = 1.0f / (1.0f + s);
}

__global__ void k_buildA(const float* __restrict__ adj, const float* __restrict__ dinv,
                         u16* __restrict__ Ab) {
  int i = blockIdx.x;
  for (int j = threadIdx.x; j < 512; j += 256) {
    float v = adj[(size_t)j * 512 + i] + ((i == j) ? 1.0f : 0.0f);
    Ab[(size_t)i * 512 + j] = f2bf(v * dinv[j]);
  }
}

// state fp32 -> SnAll slice0 (swizzled node-major bf16) AND f-major bf16 XG0t
__global__ __launch_bounds__(256) void k_prepST(const float* __restrict__ s,
                                                u16* __restrict__ Sn,
                                                u16* __restrict__ Xt) {
  __shared__ float Tl[64][65];
  const int b = blockIdx.y, n0 = blockIdx.x * 64;
  const int tid = threadIdx.x;
  const int r = tid >> 4, c4 = (tid & 15) * 4;
  const int ch = (tid & 15) >> 1, ib = (tid & 15) & 1;   // chunk 0-7, 8B-half
  #pragma unroll
  for (int i = 0; i < 4; ++i) {
    int n = n0 + i * 16 + r;
    f32x4 v = *(const f32x4*)&s[((size_t)b * 512 + n) * 64 + c4];
    s16x4 o;
    #pragma unroll
    for (int j = 0; j < 4; ++j) { Tl[c4 + j][i * 16 + r] = v[j]; o[j] = (short)f2bf(v[j]); }
    *(s16x4*)&Sn[((size_t)b * 512 + n) * 224 + 8 * (ch ^ (n & 7)) + 4 * ib] = o;
  }
  __syncthreads();
  #pragma unroll
  for (int i = 0; i < 4; ++i) {
    int d = i * 16 + r;
    s16x4 o;
    #pragma unroll
    for (int j = 0; j < 4; ++j) o[j] = (short)f2bf(Tl[d][c4 + j]);
    *(s16x4*)&Xt[((size_t)b * 64 + d) * 512 + n0 + c4] = o;
  }
}

// inp[b][m*2+c] -> Xi0t[(b*2+c)*512 + m]
__global__ void k_prepI(const float* __restrict__ inp, u16* __restrict__ Xi0t) {
  const int b = blockIdx.x, t = threadIdx.x;
  const int m2 = t * 2;
  f32x4 v = *(const f32x4*)&inp[(size_t)b * 1024 + m2 * 2];
  unsigned p0 = (unsigned)f2bf(v.x) | ((unsigned)f2bf(v.z) << 16);
  unsigned p1 = (unsigned)f2bf(v.y) | ((unsigned)f2bf(v.w) << 16);
  *(unsigned*)&Xi0t[((size_t)b * 2 + 0) * 512 + m2] = p0;
  *(unsigned*)&Xi0t[((size_t)b * 2 + 1) * 512 + m2] = p1;
}

// tail slice: chunks 24-27; content chunk (kappa 192-199) = [inp0,inp1,y10,y11,y20,y21,0,0]
__global__ void k_tail(const float* __restrict__ inp, const u16* __restrict__ Yi1,
                       const u16* __restrict__ Yi2, u16* __restrict__ Sn) {
  int idx = blockIdx.x * 256 + threadIdx.x;
  int b = idx >> 9, n = idx & 511;
  s16x8 content;
  content[0] = (short)f2bf(inp[(size_t)b * 1024 + n * 2 + 0]);
  content[1] = (short)f2bf(inp[(size_t)b * 1024 + n * 2 + 1]);
  content[2] = (short)Yi1[((size_t)b * 2 + 0) * 512 + n];
  content[3] = (short)Yi1[((size_t)b * 2 + 1) * 512 + n];
  content[4] = (short)Yi2[((size_t)b * 2 + 0) * 512 + n];
  content[5] = (short)Yi2[((size_t)b * 2 + 1) * 512 + n];
  content[6] = 0; content[7] = 0;
  s16x8 zero = {};
  size_t row = (size_t)b * 512 + n;
  #pragma unroll
  for (int q = 0; q < 4; ++q)
    *(s16x8*)&Sn[row * 224 + (24 + q) * 8] = (q == (n & 3)) ? content : zero;
}

// WTp[col][kt][g][j] permuted per-thread A-fragments, Chebyshev folded:
// k1==0 -> W0 - W2 ; k1==1 -> W1 ; k1==2 -> 2*W2
template<int NC>
__global__ void k_wtp(const float* __restrict__ W, u16* __restrict__ WTp) {
  int col = blockIdx.x, tid = threadIdx.x;
  if (tid >= 224) return;
  int kt = tid >> 5, g = (tid >> 3) & 3, j = tid & 7;
  int kappa = 32 * kt + 4 * g + ((j < 4) ? j : j + 12);
  float v = 0.0f;
  if (kappa < 192) {
    int f = kappa & 63, k1 = kappa >> 6;
    const float* base = &W[(size_t)((f + 2) * 3) * NC + col];
    v = (k1 == 0) ? base[0] - base[2 * NC]
      : (k1 == 1) ? base[1 * NC]
                  : 2.0f * base[2 * NC];
  } else if (kappa < 198) {
    int t = kappa - 192, k1 = t >> 1, c = t & 1;
    const float* base = &W[(size_t)(c * 3) * NC + col];
    v = (k1 == 0) ? base[0] - base[2 * NC]
      : (k1 == 1) ? base[1 * NC]
                  : 2.0f * base[2 * NC];
  }
  WTp[(size_t)col * 224 + tid] = f2bf(v);
}

// ---------------- diffusion GEMM: Y[R][n] = sum_m Xt[R][m]*Ab[n][m] ----------------
// Block 128R x 128n, 4 waves, BK=32, double-buffered (proven r6 skeleton).
// WTB: write Yt (f-major, LDS-bounced). SLICE>=0: write SnAll slice (batch rows).
template<int WTB, int SLICE>
__global__ __launch_bounds__(256, 3) void k_diffB(const u16* __restrict__ Xt,
                                                  const u16* __restrict__ Ab,
                                                  u16* __restrict__ Yt,
                                                  u16* __restrict__ Sn) {
  __shared__ __align__(16) u16 SB[16384];
  const int tid = threadIdx.x;
  const int w = tid >> 6, l = tid & 63, g = l >> 4, l16 = l & 15;
  const int Rg = w >> 1, ng = w & 1;
  const int nt0 = blockIdx.x * 128;
  const size_t R0 = (size_t)blockIdx.y * 128;
  const bool isInput = (R0 >= 16384);
  f32x4 acc[4][4] = {};

#define STAGE(BUF, M0)                                                            \
  {                                                                               \
    _Pragma("unroll")                                                             \
    for (int i_ = 0; i_ < 2; ++i_) {                                              \
      int s_ = i_ * 256 + tid, r_ = s_ >> 2, p_ = s_ & 3;                         \
      gload16(&Xt[(R0 + r_) * 512 + (M0) + 8 * (p_ ^ (r_ & 3))],                  \
              &SB[(BUF) * 4096 + s_ * 8]);                                        \
      gload16(&Ab[(size_t)(nt0 + r_) * 512 + (M0) + 8 * (p_ ^ (r_ & 3))],         \
              &SB[8192 + (BUF) * 4096 + s_ * 8]);                                 \
    }                                                                             \
  }

  STAGE(0, 0);
  #pragma unroll
  for (int it = 0; it < 16; ++it) {
    const int cur = it & 1;
    if (it < 15) {
      if (cur == 0) STAGE(1, (it + 1) * 32)
      else          STAGE(0, (it + 1) * 32)
      asm volatile("s_waitcnt vmcnt(4)" ::: "memory");
    } else {
      asm volatile("s_waitcnt vmcnt(0)" ::: "memory");
    }
    __builtin_amdgcn_s_barrier();
    __builtin_amdgcn_sched_barrier(0);

    const u16* XL = &SB[cur * 4096];
    const u16* AL = &SB[8192 + cur * 4096];
    s16x8 af[4], bf[4];
    #pragma unroll
    for (int mt = 0; mt < 4; ++mt) {
      int r = Rg * 64 + mt * 16 + l16;
      const char* rowp = (const char*)XL + r * 64 + 8 * (g & 1);
      int c0 = (g >> 1), c1 = c0 + 2;
      s16x4 lo = *(const s16x4*)(rowp + 16 * (c0 ^ (r & 3)));
      s16x4 hi = *(const s16x4*)(rowp + 16 * (c1 ^ (r & 3)));
      af[mt] = __builtin_shufflevector(lo, hi, 0, 1, 2, 3, 4, 5, 6, 7);
    }
    #pragma unroll
    for (int nt = 0; nt < 4; ++nt) {
      int r = ng * 64 + nt * 16 + l16;
      const char* rowp = (const char*)AL + r * 64 + 8 * (g & 1);
      int c0 = (g >> 1), c1 = c0 + 2;
      s16x4 lo = *(const s16x4*)(rowp + 16 * (c0 ^ (r & 3)));
      s16x4 hi = *(const s16x4*)(rowp + 16 * (c1 ^ (r & 3)));
      bf[nt] = __builtin_shufflevector(lo, hi, 0, 1, 2, 3, 4, 5, 6, 7);
    }
    #pragma unroll
    for (int mt = 0; mt < 4; ++mt)
      #pragma unroll
      for (int nt = 0; nt < 4; ++nt)
        acc[mt][nt] = __builtin_amdgcn_mfma_f32_16x16x32_bf16(af[mt], bf[nt],
                                                              acc[mt][nt], 0, 0, 0);
    __builtin_amdgcn_s_barrier();
    __builtin_amdgcn_sched_barrier(0);
  }
#undef STAGE

  if (SLICE >= 0 && !isInput) {
    #pragma unroll
    for (int mt = 0; mt < 4; ++mt)
      #pragma unroll
      for (int nt = 0; nt < 4; ++nt) {
        int f0 = mt * 16 + 4 * g;
        int b = (int)(R0 >> 6) + Rg;
        int n = nt0 + ng * 64 + nt * 16 + l16;
        s16x4 o;
        #pragma unroll
        for (int rr = 0; rr < 4; ++rr) o[rr] = (short)f2bf(acc[mt][nt][rr]);
        int c = SLICE / 8 + 2 * mt + (g >> 1);        // chunk (8..23)
        *(s16x4*)&Sn[((size_t)b * 512 + n) * 224 + 8 * (c ^ (n & 7)) + 4 * (g & 1)] = o;
      }
  }

  if (WTB || isInput) {
    #pragma unroll
    for (int mt = 0; mt < 4; ++mt)
      #pragma unroll
      for (int nt = 0; nt < 4; ++nt) {
        int nl = ng * 64 + nt * 16 + l16;
        #pragma unroll
        for (int rr = 0; rr < 4; ++rr) {
          int Rl = Rg * 64 + mt * 16 + 4 * g + rr;
          SB[Rl * 128 + nl] = f2bf(acc[mt][nt][rr]);
        }
      }
    __syncthreads();
    #pragma unroll
    for (int i = 0; i < 8; ++i) {
      int s = i * 256 + tid, r = s >> 4, c = s & 15;
      *(s16x8*)&Yt[(R0 + r) * 512 + nt0 + c * 8] = *(const s16x8*)&SB[r * 128 + c * 8];
    }
  }
}

// ---------------- pipelined applyW: 4 node-tiles/block, double-buffered SnAll staging ----
// ISGATE: r->SnAll slice0 (rs, swizzled) + XC0t scalar, u->outp fp32.
// else:   out = u*state + (1-u)*tanh(.), u read from outp.
template<int ISGATE>
__global__ __launch_bounds__(256, 2) void k_apply(
    const u16* __restrict__ Sn, const u16* __restrict__ WTp,
    const float* __restrict__ bias, const float* __restrict__ statef,
    u16* __restrict__ SnRS, u16* __restrict__ XC0t, float* __restrict__ outp) {
  __shared__ __align__(16) u16 SB[2][14336];   // 2 x 64 rows x 224
  const int tid = threadIdx.x;
  const int w = tid >> 6, l = tid & 63, g = l >> 4, l16 = l & 15;
  const int b = blockIdx.y, x = blockIdx.x;
  const int colr = w * 16 + l16;

  constexpr int NCF = ISGATE ? 2 : 1;
  s16x8 aw[7][NCF];
  #pragma unroll
  for (int cf = 0; cf < NCF; ++cf) {
    const u16* wp = WTp + (size_t)(colr + cf * 64) * 224 + g * 8;
    #pragma unroll
    for (int kt = 0; kt < 7; ++kt) aw[kt][cf] = *(const s16x8*)&wp[kt * 32];
  }

#define ASTG(BUF, T)                                                              \
  {                                                                               \
    size_t row0_ = (size_t)b * 512 + ((x << 2) + (T)) * 64;                       \
    _Pragma("unroll")                                                             \
    for (int it_ = 0; it_ < 7; ++it_) {                                           \
      int s_ = it_ * 256 + tid;                                                   \
      int r_ = s_ / 28, p_ = s_ % 28;                                             \
      gload16(&Sn[(row0_ + r_) * 224 + p_ * 8], &SB[BUF][(it_ * 256 + w * 64) * 8]); \
    }                                                                             \
  }

  ASTG(0, 0);
  #pragma unroll
  for (int t = 0; t < 4; ++t) {
    if (t < 3) {
      if ((t & 1) == 0) ASTG(1, t + 1) else ASTG(0, t + 1)
      asm volatile("s_waitcnt vmcnt(7)" ::: "memory");
    } else {
      asm volatile("s_waitcnt vmcnt(0)" ::: "memory");
    }
    __builtin_amdgcn_s_barrier();
    __builtin_amdgcn_sched_barrier(0);

    const u16* B = &SB[t & 1][0];
    f32x4 aacc[NCF][4];
    #pragma unroll
    for (int cf = 0; cf < NCF; ++cf)
      #pragma unroll
      for (int ns = 0; ns < 4; ++ns) aacc[cf][ns] = f32x4{0.f, 0.f, 0.f, 0.f};

    #pragma unroll
    for (int kt = 0; kt < 7; ++kt) {
      #pragma unroll
      for (int ns = 0; ns < 4; ++ns) {
        int rn = ns * 16 + l16;
        int c0 = kt * 4 + (g >> 1), c1 = c0 + 2;
        int p0 = (c0 < 24) ? (c0 ^ (rn & 7)) : (24 + ((c0 - 24) ^ (rn & 3)));
        int p1 = (c1 < 24) ? (c1 ^ (rn & 7)) : (24 + ((c1 - 24) ^ (rn & 3)));
        const char* rowp = (const char*)B + rn * 448 + 8 * (g & 1);
        s16x4 lo = *(const s16x4*)(rowp + 16 * p0);
        s16x4 hi = *(const s16x4*)(rowp + 16 * p1);
        s16x8 bs = __builtin_shufflevector(lo, hi, 0, 1, 2, 3, 4, 5, 6, 7);
        #pragma unroll
        for (int cf = 0; cf < NCF; ++cf)
          aacc[cf][ns] = __builtin_amdgcn_mfma_f32_16x16x32_bf16(aw[kt][cf], bs,
                                                                 aacc[cf][ns], 0, 0, 0);
      }
    }

    const int nt0 = ((x << 2) + t) * 64;
    if (ISGATE) {
      f32x4 b4r = *(const f32x4*)&bias[w * 16 + 4 * g];
      f32x4 b4u = *(const f32x4*)&bias[64 + w * 16 + 4 * g];
      const int ch = 2 * w + (g >> 1);
      #pragma unroll
      for (int ns = 0; ns < 4; ++ns) {
        int rn = ns * 16 + l16;
        int n = nt0 + rn;
        size_t row = (size_t)b * 512 + n;
        size_t base = row * 64 + w * 16 + 4 * g;
        const char* rowp = (const char*)B + rn * 448;
        s16x4 st4 = *(const s16x4*)(rowp + 16 * (ch ^ (rn & 7)) + 8 * (g & 1));
        s16x4 o;
        #pragma unroll
        for (int rr = 0; rr < 4; ++rr) {
          float xv = aacc[0][ns][rr] + b4r[rr];
          float sg = 1.0f / (1.0f + expf(-xv));
          o[rr] = (short)f2bf(sg * bf2f((u16)st4[rr]));
        }
        *(s16x4*)&SnRS[row * 224 + 8 * (ch ^ (n & 7)) + 4 * (g & 1)] = o;
        #pragma unroll
        for (int rr = 0; rr < 4; ++rr)
          XC0t[((size_t)b * 64 + w * 16 + 4 * g + rr) * 512 + n] = (u16)o[rr];
        f32x4 uo;
        #pragma unroll
        for (int rr = 0; rr < 4; ++rr) {
          float xv = aacc[1][ns][rr] + b4u[rr];
          uo[rr] = 1.0f / (1.0f + expf(-xv));
        }
        *(f32x4*)&outp[base] = uo;   // u stashed in d_out
      }
    } else {
      f32x4 b4 = *(const f32x4*)&bias[w * 16 + 4 * g];
      #pragma unroll
      for (int ns = 0; ns < 4; ++ns) {
        int n = nt0 + ns * 16 + l16;
        size_t base = ((size_t)b * 512 + n) * 64 + w * 16 + 4 * g;
        f32x4 u4 = *(const f32x4*)&outp[base];
        f32x4 st4 = *(const f32x4*)&statef[base];
        f32x4 o;
        #pragma unroll
        for (int rr = 0; rr < 4; ++rr) {
          float c = tanhf(aacc[0][ns][rr] + b4[rr]);
          o[rr] = fmaf(u4[rr], st4[rr] - c, c);
        }
        *(f32x4*)&outp[base] = o;
      }
    }
    __builtin_amdgcn_s_barrier();   // protect buf overwrite next iter
  }
#undef ASTG
}

extern "C" void kernel_launch(void* const* d_in, const int* in_sizes, int n_in,
                              void* d_out, int out_size, void* d_ws, size_t ws_size,
                              hipStream_t stream) {
  const float* inp   = (const float*)d_in[0];
  const float* state = (const float*)d_in[1];
  const float* adj   = (const float*)d_in[2];
  const float* Wg    = (const float*)d_in[3];
  const float* bg    = (const float*)d_in[4];
  const float* Wc    = (const float*)d_in[5];
  const float* bc    = (const float*)d_in[6];
  float* out = (float*)d_out;

  char* p = (char*)d_ws;
  u16* Abf    = (u16*)p; p += 524288;      // Ab[n][m]
  u16* XAll0t = (u16*)p; p += 17301504;    // [16896][512]: XG0t (later XC0t) + Xi0t tail
  u16* X1t    = (u16*)p; p += 17301504;    // [16896][512]: X1t batch + Yi1t tail
  u16* Yi2t   = (u16*)p; p += 524288;      // [512][512] (plain A@Yi1; weights folded)
  u16* WTpg   = (u16*)p; p += 57344;       // [128][224] permuted + folded
  u16* WTpc   = (u16*)p; p += 28672;       // [64][224]
  float* dinv = (float*)p; p += 2048;
  u16* SnAll  = (u16*)p; p += 58720256;    // [b*512+n][224] swizzled  (total ~94.5 MB)
  u16* Xi0t   = XAll0t + (size_t)16384 * 512;
  u16* XC0t   = XAll0t;                    // alias: XG0t dead after gate hop1
  u16* Yi1t   = X1t + (size_t)16384 * 512;

  k_dinv   <<<512, 64,  0, stream>>>(adj, dinv);
  k_buildA <<<512, 256, 0, stream>>>(adj, dinv, Abf);
  k_prepST <<<dim3(8, 256), 256, 0, stream>>>(state, SnAll, XAll0t);
  k_prepI  <<<256, 256, 0, stream>>>(inp, Xi0t);
  k_wtp<128><<<128, 256, 0, stream>>>(Wg, WTpg);
  k_wtp<64> <<<64, 256, 0, stream>>>(Wc, WTpc);

  // gate hop1 (batch + input rows) -> X1t (+Yi1t tail) and SnAll slice64
  k_diffB<1, 64><<<dim3(4, 132), 256, 0, stream>>>(XAll0t, Abf, X1t, SnAll);
  // input hop2: Yi2 = A @ Yi1 (plain, folded)
  k_diffB<1, -1><<<dim3(4, 4), 256, 0, stream>>>(Yi1t, Abf, Yi2t, nullptr);
  // tail slice
  k_tail <<<512, 256, 0, stream>>>(inp, Yi1t, Yi2t, SnAll);
  // gate hop2 -> SnAll slice128 only
  k_diffB<0, 128><<<dim3(4, 128), 256, 0, stream>>>(X1t, Abf, nullptr, SnAll);
  // gate apply: rs -> SnAll slice0 + XC0t, u -> out (fp32)
  k_apply<1><<<dim3(2, 256), 256, 0, stream>>>(SnAll, WTpg, bg, nullptr,
                                               SnAll, XC0t, out);
  // cand hop1 -> X1t + slice64 ; cand hop2 -> slice128
  k_diffB<1, 64><<<dim3(4, 128), 256, 0, stream>>>(XC0t, Abf, X1t, SnAll);
  k_diffB<0, 128><<<dim3(4, 128), 256, 0, stream>>>(X1t, Abf, nullptr, SnAll);
  // cand apply -> out
  k_apply<0><<<dim3(2, 256), 256, 0, stream>>>(SnAll, WTpc, bc, state,
                                               nullptr, nullptr, out);
}